// Round 9
// baseline (98.704 us; speedup 1.0000x reference)
//
#include <hip/hip_runtime.h>

// BoundaryLoss: B=8, C=4, H=W=384
//   probs = softmax(logits, axis=1)
//   per (b,c): mask = (targets==c); phi = sqrt(edt2(mask)) - sqrt(edt2(~mask)) + 1
//   out = mean(probs * phi)
//
// R9 = R8 + k_fused staging rework:
//   - uint4 staging: one thread stages a full 32-B row segment (16 u16) per
//     class with 2 global_load_dwordx4 (was 16 scalar 2-B loads). 8 vector
//     loads/thread replace 64 scalar loads + address VALU.
//   - classes 2,3 PREFETCHED into registers before phase-0 compute; phase-1
//     staging is unpack+ds_write only (global latency hidden behind phase-0).
//   - compute mapping unchanged from R8 (wave = 4 consecutive rows x 16 cols:
//     correlated trip counts, 2-way LDS banks = free).
// Grid 768 = 8b x 24 tiles(16 cols, 64-B aligned) x 4 row-quarters;
// LDS 52.2 KB -> 3 blocks/CU = 4.5 waves/SIMD.
//
// Key identity (R4): neg2_c == min_{c'!=c} pos2_{c'} bitwise; sqrt monotone
// => neg_c = min_{c'!=c} r_{c'}. Only per-class POS row EDTs are computed.
// s==0 / s==HW cases dead (every class in every row, p < e^-110).
// All finite EDT arithmetic is exact small ints in f32; min(a,b)+dd ==
// min(a+dd,b+dd) exactly (rounding monotone) -> distances bitwise-identical
// to the reference min-plus.

#define BB 8
#define CC 4
#define HH 384
#define WW 384
#define HW (HH * WW)
#define NTOT 4718592.0f

__global__ __launch_bounds__(384) void k_rowedt(const int* __restrict__ targets,
                                                unsigned short* __restrict__ edt16,
                                                float* __restrict__ out) {
    const int blk = blockIdx.x;          // b*HH + i
    const int b = blk / HH;
    const int i = blk - b * HH;
    const int j = threadIdx.x;           // 0..383
    const int wv = j >> 6, ln = j & 63;

    __shared__ unsigned long long msk[CC][6];
    const int tj = targets[((size_t)b * HH + i) * WW + j];

    #pragma unroll
    for (int c = 0; c < CC; ++c) {
        const unsigned long long m = __ballot(tj == c);
        if (ln == 0) msk[c][wv] = m;
    }
    __syncthreads();

    #pragma unroll
    for (int c = 0; c < CC; ++c) {
        const unsigned long long w = msk[c][wv];
        int dR = 0xFFFF;
        const unsigned long long x = (ln == 63) ? 0ull : (w >> (ln + 1));
        if (x) {
            dR = __builtin_ctzll(x) + 1;
        } else {
            for (int k = wv + 1; k < 6; ++k) {
                const unsigned long long wk = msk[c][k];
                if (wk) { dR = 64 * k + __builtin_ctzll(wk) - j; break; }
            }
        }
        int dL = 0xFFFF;
        const unsigned long long y = (ln == 0) ? 0ull : (w << (64 - ln));
        if (y) {
            dL = __builtin_clzll(y) + 1;
        } else {
            for (int k = wv - 1; k >= 0; --k) {
                const unsigned long long wk = msk[c][k];
                if (wk) { dL = j - (64 * k + 63 - __builtin_clzll(wk)); break; }
            }
        }
        const int fd = (tj == c) ? 0 : (dR < dL ? dR : dL);   // own class -> 0
        edt16[(size_t)(b * CC + c) * HW + (size_t)i * WW + j] = (unsigned short)fd;
    }

    if (blk == 0 && j == 0) out[0] = 0.0f;   // zero accumulator (no memset node)
}

// unpack 16 u16 distances (two uint4) -> 16 f32 squares at dst[0..15]
__device__ __forceinline__ void store_sq16(float* __restrict__ dst, uint4 x, uint4 y) {
    const unsigned int w[8] = {x.x, x.y, x.z, x.w, y.x, y.y, y.z, y.w};
    #pragma unroll
    for (int h = 0; h < 8; ++h) {
        const unsigned int lo = w[h] & 0xFFFFu;
        const unsigned int hi = w[h] >> 16;
        dst[2 * h]     = (float)(lo * lo);   // exact ints in f32
        dst[2 * h + 1] = (float)(hi * hi);
    }
}

__global__ __launch_bounds__(384) void k_fused(const unsigned short* __restrict__ edt16,
                                               const float* __restrict__ logits,
                                               float* __restrict__ out) {
    const int blk = blockIdx.x;            // ((b*24 + tile)*4 + q), 768 blocks
    const int q = blk & 3;                 // row quarter: rows [96q, 96q+96)
    const int bt = blk >> 2;
    const int b = bt / 24;
    const int tile = bt - b * 24;
    const int j0 = tile * 16;              // 64-B aligned
    const int col = threadIdx.x & 15;
    const int rg  = threadIdx.x >> 4;      // 0..23

    __shared__ float sq[2][HH][17];        // 52,224 B -> 3 blocks/CU

    // ---- staging loads: thread t owns row t's 32-B segment, all 4 classes ----
    const int t = threadIdx.x;             // 0..383 == row index
    const unsigned short* g =
        edt16 + (size_t)b * CC * HW + (size_t)t * WW + j0;   // 16-B aligned
    const uint4 a0 = *(const uint4*)(g);                // class0 cols 0..7
    const uint4 a1 = *(const uint4*)(g + 8);            // class0 cols 8..15
    const uint4 b0 = *(const uint4*)(g + HW);           // class1
    const uint4 b1 = *(const uint4*)(g + HW + 8);
    const uint4 c0 = *(const uint4*)(g + 2 * (size_t)HW);       // class2 (prefetch)
    const uint4 c1 = *(const uint4*)(g + 2 * (size_t)HW + 8);
    const uint4 d0 = *(const uint4*)(g + 3 * (size_t)HW);       // class3 (prefetch)
    const uint4 d1 = *(const uint4*)(g + 3 * (size_t)HW + 8);

    store_sq16(&sq[0][t][0], a0, a1);
    store_sq16(&sq[1][t][0], b0, b1);
    __syncthreads();

    // ---- phase 0 compute: classes 0,1 (fused 2-chain min-plus) ----
    float r01[2][4];
    #pragma unroll
    for (int k = 0; k < 4; ++k) {
        const int i = q * 96 + rg + 24 * k;
        float e0_ = sq[0][i][col];
        float e1_ = sq[1][i][col];
        float dd = 1.0f, odd = 3.0f;
        int lo = i, hi = i;
        while (dd < fmaxf(e0_, e1_)) {     // finished chain: cand>=dd>=best, no-op
            lo = (lo > 0) ? lo - 1 : 0;    // clamped cand dominated by earlier one
            hi = (hi < HH - 1) ? hi + 1 : HH - 1;
            e0_ = fminf(e0_, fminf(sq[0][lo][col], sq[0][hi][col]) + dd);
            e1_ = fminf(e1_, fminf(sq[1][lo][col], sq[1][hi][col]) + dd);
            dd += odd; odd += 2.0f;        // dd = d*d exactly
        }
        r01[0][k] = sqrtf(e0_);
        r01[1][k] = sqrtf(e1_);
    }
    __syncthreads();                       // all phase-0 reads done

    // ---- phase 1 staging (registers -> LDS only) ----
    store_sq16(&sq[0][t][0], c0, c1);
    store_sq16(&sq[1][t][0], d0, d1);
    __syncthreads();

    // ---- phase 1 compute + loss ----
    float acc = 0.0f;
    #pragma unroll
    for (int k = 0; k < 4; ++k) {
        const int i = q * 96 + rg + 24 * k;
        float e2_ = sq[0][i][col];
        float e3_ = sq[1][i][col];
        float dd = 1.0f, odd = 3.0f;
        int lo = i, hi = i;
        while (dd < fmaxf(e2_, e3_)) {
            lo = (lo > 0) ? lo - 1 : 0;
            hi = (hi < HH - 1) ? hi + 1 : HH - 1;
            e2_ = fminf(e2_, fminf(sq[0][lo][col], sq[0][hi][col]) + dd);
            e3_ = fminf(e3_, fminf(sq[1][lo][col], sq[1][hi][col]) + dd);
            dd += odd; odd += 2.0f;
        }
        const float r0 = r01[0][k];
        const float r1 = r01[1][k];
        const float r2 = sqrtf(e2_);
        const float r3 = sqrtf(e3_);

        // neg_c = min over other classes (sqrt monotone => bitwise == ref)
        const float p0 = r0 - fminf(r1, fminf(r2, r3)) + 1.0f;
        const float p1 = r1 - fminf(r0, fminf(r2, r3)) + 1.0f;
        const float p2 = r2 - fminf(r0, fminf(r1, r3)) + 1.0f;
        const float p3 = r3 - fminf(r0, fminf(r1, r2)) + 1.0f;

        const size_t po = (size_t)i * WW + j0 + col;
        const size_t pb = (size_t)b * CC * HW;
        const float l0 = logits[pb + 0 * HW + po];
        const float l1 = logits[pb + 1 * HW + po];
        const float l2 = logits[pb + 2 * HW + po];
        const float l3 = logits[pb + 3 * HW + po];
        const float m  = fmaxf(fmaxf(l0, l1), fmaxf(l2, l3));
        const float x0 = __expf(l0 - m), x1 = __expf(l1 - m);
        const float x2 = __expf(l2 - m), x3 = __expf(l3 - m);
        const float inv = 1.0f / (x0 + x1 + x2 + x3);
        acc += inv * (x0 * p0 + x1 * p1 + x2 * p2 + x3 * p3);
    }

    #pragma unroll
    for (int off = 32; off > 0; off >>= 1) acc += __shfl_down(acc, off, 64);
    __shared__ float wsum[6];
    const int wid = threadIdx.x >> 6, ln = threadIdx.x & 63;
    if (ln == 0) wsum[wid] = acc;
    __syncthreads();
    if (threadIdx.x == 0) {
        float tot = 0.0f;
        #pragma unroll
        for (int w = 0; w < 6; ++w) tot += wsum[w];
        atomicAdd(out, tot * (1.0f / NTOT));
    }
}

extern "C" void kernel_launch(void* const* d_in, const int* in_sizes, int n_in,
                              void* d_out, int out_size, void* d_ws, size_t ws_size,
                              hipStream_t stream) {
    const float* logits  = (const float*)d_in[0];
    const int*   targets = (const int*)d_in[1];
    float* out = (float*)d_out;
    unsigned short* edt16 = (unsigned short*)d_ws;

    hipLaunchKernelGGL(k_rowedt, dim3(BB * HH), dim3(WW), 0, stream, targets, edt16, out);
    hipLaunchKernelGGL(k_fused,  dim3(BB * 24 * 4), dim3(384), 0, stream, edt16, logits, out);
}